// Round 5
// baseline (371.730 us; speedup 1.0000x reference)
//
#include <hip/hip_runtime.h>
#include <stdint.h>

#define SEQ 2048
#define HIDDEN 1024
#define NHEADS 16
#define HDIM 64
#define MTOT 8192  // B*SEQ

// 1/sqrt(HDIM) * log2(e), folded into wq/bq so attn does exp2(S) directly
#define C1SCALE 0.1803368801111437f

typedef __bf16 bf16x8 __attribute__((ext_vector_type(8)));
typedef unsigned short u16x8 __attribute__((ext_vector_type(8)));
typedef short s16x4 __attribute__((ext_vector_type(4)));
typedef unsigned int u32x4 __attribute__((ext_vector_type(4)));
typedef float f32x4 __attribute__((ext_vector_type(4)));

#define GAS __attribute__((address_space(1)))
#define LAS __attribute__((address_space(3)))

__device__ __forceinline__ unsigned short bf16_rne(float f) {
  union { float f; unsigned int u; } v; v.f = f;
  return (unsigned short)((v.u + 0x7fffu + ((v.u >> 16) & 1u)) >> 16);
}

// pack 2 f32 -> 2 bf16 (RNE) in one dword via v_cvt_pk_bf16_f32 (T12 recipe;
// no builtin on gfx950). D[15:0]=bf16(lo), D[31:16]=bf16(hi).
__device__ __forceinline__ unsigned int pkcvt(float lo, float hi) {
  unsigned int r;
  asm("v_cvt_pk_bf16_f32 %0, %1, %2" : "=v"(r) : "v"(lo), "v"(hi));
  return r;
}

__device__ __forceinline__ void gload_lds16(const unsigned short* g, unsigned short* l) {
  __builtin_amdgcn_global_load_lds((GAS void*)(unsigned short*)g, (LAS void*)l, 16, 0, 0);
}

// ---------------- fused fp32 -> bf16 conversions ---------------------------
__global__ __launch_bounds__(256) void cvt3(const float* __restrict__ a,
                                            const float* __restrict__ b,
                                            const float* __restrict__ c,
                                            unsigned short* __restrict__ out,
                                            int perSeg) {
  const int seg = blockIdx.y;
  const float* in = seg == 0 ? a : (seg == 1 ? b : c);
  int i = blockIdx.x * 256 + threadIdx.x;
  float4 v = ((const float4*)in)[i];
  ushort4 o;
  o.x = bf16_rne(v.x); o.y = bf16_rne(v.y);
  o.z = bf16_rne(v.z); o.w = bf16_rne(v.w);
  ((ushort4*)(out + (size_t)seg * perSeg))[i] = o;
}

// seg 0 (wq) is pre-scaled by C1SCALE (softmax scale folded into Q projection)
__global__ __launch_bounds__(256) void cvt4(const float* __restrict__ a,
                                            const float* __restrict__ b,
                                            const float* __restrict__ c,
                                            const float* __restrict__ d,
                                            unsigned short* __restrict__ out,
                                            int perSeg) {
  const int seg = blockIdx.y;
  const float* in = seg == 0 ? a : (seg == 1 ? b : (seg == 2 ? c : d));
  const float sc = (seg == 0) ? C1SCALE : 1.0f;
  int i = blockIdx.x * 256 + threadIdx.x;
  float4 v = ((const float4*)in)[i];
  ushort4 o;
  o.x = bf16_rne(v.x * sc); o.y = bf16_rne(v.y * sc);
  o.z = bf16_rne(v.z * sc); o.w = bf16_rne(v.w * sc);
  ((ushort4*)(out + (size_t)seg * perSeg))[i] = o;
}

// ---------------- fused QKV GEMM -------------------------------------------
// v5: double-buffered LDS pipeline (attn7 pattern): stage(k+1) issued right
// after the per-step barrier -> DMA in flight across the whole compute(k)
// phase; ONE barrier/step (was 2, with fully serial stage->compute).
// XCD-aware bijective swizzle (nwg=1536). seg==2 (V) epilogue writes the attn
// PV fragment-linear Vt layout directly.
__global__ __launch_bounds__(256) void gemm_qkv(const unsigned short* __restrict__ Xq,
                                                const unsigned short* __restrict__ Xk,
                                                const unsigned short* __restrict__ Xv,
                                                const unsigned short* __restrict__ W,
                                                const float* __restrict__ bq,
                                                const float* __restrict__ bk,
                                                const float* __restrict__ bv,
                                                unsigned short* __restrict__ Qb,
                                                unsigned short* __restrict__ Kb,
                                                unsigned short* __restrict__ Vt) {
  __shared__ unsigned short As[2][128 * 32];
  __shared__ unsigned short Bs[2][128 * 32];
  const int tid = threadIdx.x;
  const int lane = tid & 63, w = tid >> 6;
  const int quad = lane >> 4, ln = lane & 15;
  const int wm = w & 1, wn = w >> 1;
  // XCD swizzle: flat dispatch id -> contiguous work chunk per XCD
  const int flat = blockIdx.y * 24 + blockIdx.x;
  const int wid = (flat & 7) * 192 + (flat >> 3);
  const int mIdx = wid / 24, nIdx = wid % 24;
  const int mBase = mIdx * 128, nBase = (nIdx & 7) * 128;
  const int seg = nIdx >> 3;
  const unsigned short* A = seg == 0 ? Xq : (seg == 1 ? Xk : Xv);
  const float* bias = seg == 0 ? bq : (seg == 1 ? bk : bv);
  const float bscale = seg == 0 ? C1SCALE : 1.0f;
  const int K = HIDDEN;

  f32x4 acc[4][4];
  f32x4 zero = {0.f, 0.f, 0.f, 0.f};
#pragma unroll
  for (int i = 0; i < 4; i++)
#pragma unroll
    for (int j = 0; j < 4; j++) acc[i][j] = zero;

  const int e0 = tid * 8;
  const int e1 = (256 + tid) * 8;
  const int r0 = e0 >> 5, c0 = e0 & 31;
  const int r1 = e1 >> 5, c1 = e1 & 31;
  const unsigned short* Ap0 = A + (size_t)(mBase + r0) * K + c0;
  const unsigned short* Ap1 = A + (size_t)(mBase + r1) * K + c1;
  const unsigned short* Wp0 = W + (size_t)(seg * HIDDEN + nBase + r0) * K + c0;
  const unsigned short* Wp1 = W + (size_t)(seg * HIDDEN + nBase + r1) * K + c1;

  // prologue: stage K-step 0 into buf 0
  gload_lds16(Ap0, &As[0][e0]);
  gload_lds16(Ap1, &As[0][e1]);
  gload_lds16(Wp0, &Bs[0][e0]);
  gload_lds16(Wp1, &Bs[0][e1]);

  for (int k = 0; k < 32; ++k) {
    __syncthreads();  // drains stage(k) DMA (issued one step earlier)
    const int cur = k & 1;
    if (k < 31) {  // stage k+1 into the other buffer (read last at step k-1)
      const int k0 = (k + 1) * 32;
      gload_lds16(Ap0 + k0, &As[cur ^ 1][e0]);
      gload_lds16(Ap1 + k0, &As[cur ^ 1][e1]);
      gload_lds16(Wp0 + k0, &Bs[cur ^ 1][e0]);
      gload_lds16(Wp1 + k0, &Bs[cur ^ 1][e1]);
    }
    u16x8 af[4], bfr[4];
#pragma unroll
    for (int mi = 0; mi < 4; mi++)
      af[mi] = *(const u16x8*)&As[cur][(wm * 64 + mi * 16 + ln) * 32 + quad * 8];
#pragma unroll
    for (int ni = 0; ni < 4; ni++)
      bfr[ni] = *(const u16x8*)&Bs[cur][(wn * 64 + ni * 16 + ln) * 32 + quad * 8];
#pragma unroll
    for (int mi = 0; mi < 4; mi++)
#pragma unroll
      for (int ni = 0; ni < 4; ni++)
        acc[mi][ni] = __builtin_amdgcn_mfma_f32_16x16x32_bf16(
            __builtin_bit_cast(bf16x8, af[mi]), __builtin_bit_cast(bf16x8, bfr[ni]),
            acc[mi][ni], 0, 0, 0);
  }

  if (seg < 2) {
    unsigned short* outp = seg == 0 ? Qb : Kb;
#pragma unroll
    for (int ni = 0; ni < 4; ni++) {
      const int col = nBase + wn * 64 + ni * 16 + ln;
      const float bvv = bias[col] * bscale;
#pragma unroll
      for (int mi = 0; mi < 4; mi++) {
        const int row = mBase + wm * 64 + mi * 16 + quad * 4;
#pragma unroll
        for (int r = 0; r < 4; r++)
          outp[(size_t)(row + r) * HIDDEN + col] = bf16_rne(acc[mi][ni][r] + bvv);
      }
    }
  } else {
    // fused Vt epilogue (fragment-linear, PV-permuted)
    const int b = mBase >> 11;
    const int kt = (mBase & 2047) >> 7;
    const int h = (nBase >> 6) + wn;
    unsigned short* tb = Vt + (((size_t)(b * NHEADS + h) * 16 + kt) * 8192) + lane * 8;
#pragma unroll
    for (int ni = 0; ni < 4; ni++) {
      const int col = nBase + wn * 64 + ni * 16 + ln;
      const float bvv = bias[col];
#pragma unroll
      for (int p = 0; p < 2; p++) {
        const int f = (wm * 2 + p) * 4 + ni;
        u32x4 ov;
        ov[0] = pkcvt(acc[2 * p][ni][0] + bvv, acc[2 * p][ni][1] + bvv);
        ov[1] = pkcvt(acc[2 * p][ni][2] + bvv, acc[2 * p][ni][3] + bvv);
        ov[2] = pkcvt(acc[2 * p + 1][ni][0] + bvv, acc[2 * p + 1][ni][1] + bvv);
        ov[3] = pkcvt(acc[2 * p + 1][ni][2] + bvv, acc[2 * p + 1][ni][3] + bvv);
        *(u32x4*)(tb + f * 512) = ov;
      }
    }
  }
}

// ---------------- final GEMM (fp32 out) ------------------------------------
// Same dbuf single-barrier pipeline as gemm_qkv (512 blocks = only 2/CU ->
// cross-block overlap can't cover stage latency; in-block pipeline must).
__global__ __launch_bounds__(256) void gemm_f(const unsigned short* __restrict__ A,
                                              const unsigned short* __restrict__ W,
                                              const float* __restrict__ bias,
                                              float* __restrict__ Cv) {
  __shared__ unsigned short As[2][128 * 32];
  __shared__ unsigned short Bs[2][128 * 32];
  const int tid = threadIdx.x;
  const int lane = tid & 63, w = tid >> 6;
  const int quad = lane >> 4, ln = lane & 15;
  const int wm = w & 1, wn = w >> 1;
  // XCD swizzle (nwg=512, 512%8==0): 64 consecutive work-ids per XCD
  const int flat = blockIdx.y * 8 + blockIdx.x;
  const int wid = (flat & 7) * 64 + (flat >> 3);
  const int mBase = (wid >> 3) * 128, nBase = (wid & 7) * 128;
  const int K = HIDDEN, N = HIDDEN;

  f32x4 acc[4][4];
  f32x4 zero = {0.f, 0.f, 0.f, 0.f};
#pragma unroll
  for (int i = 0; i < 4; i++)
#pragma unroll
    for (int j = 0; j < 4; j++) acc[i][j] = zero;

  const int e0 = tid * 8;
  const int e1 = (256 + tid) * 8;
  const int r0 = e0 >> 5, c0 = e0 & 31;
  const int r1 = e1 >> 5, c1 = e1 & 31;
  const unsigned short* Ap0 = A + (size_t)(mBase + r0) * K + c0;
  const unsigned short* Ap1 = A + (size_t)(mBase + r1) * K + c1;
  const unsigned short* Wp0 = W + (size_t)(nBase + r0) * K + c0;
  const unsigned short* Wp1 = W + (size_t)(nBase + r1) * K + c1;

  gload_lds16(Ap0, &As[0][e0]);
  gload_lds16(Ap1, &As[0][e1]);
  gload_lds16(Wp0, &Bs[0][e0]);
  gload_lds16(Wp1, &Bs[0][e1]);

  for (int k = 0; k < 32; ++k) {
    __syncthreads();
    const int cur = k & 1;
    if (k < 31) {
      const int k0 = (k + 1) * 32;
      gload_lds16(Ap0 + k0, &As[cur ^ 1][e0]);
      gload_lds16(Ap1 + k0, &As[cur ^ 1][e1]);
      gload_lds16(Wp0 + k0, &Bs[cur ^ 1][e0]);
      gload_lds16(Wp1 + k0, &Bs[cur ^ 1][e1]);
    }
    u16x8 af[4], bfr[4];
#pragma unroll
    for (int mi = 0; mi < 4; mi++)
      af[mi] = *(const u16x8*)&As[cur][(wm * 64 + mi * 16 + ln) * 32 + quad * 8];
#pragma unroll
    for (int ni = 0; ni < 4; ni++)
      bfr[ni] = *(const u16x8*)&Bs[cur][(wn * 64 + ni * 16 + ln) * 32 + quad * 8];
#pragma unroll
    for (int mi = 0; mi < 4; mi++)
#pragma unroll
      for (int ni = 0; ni < 4; ni++)
        acc[mi][ni] = __builtin_amdgcn_mfma_f32_16x16x32_bf16(
            __builtin_bit_cast(bf16x8, af[mi]), __builtin_bit_cast(bf16x8, bfr[ni]),
            acc[mi][ni], 0, 0, 0);
  }

#pragma unroll
  for (int ni = 0; ni < 4; ni++) {
    const int col = nBase + wn * 64 + ni * 16 + ln;
    const float bvv = bias[col];
#pragma unroll
    for (int mi = 0; mi < 4; mi++) {
      const int row = mBase + wm * 64 + mi * 16 + quad * 4;
#pragma unroll
      for (int r = 0; r < 4; r++)
        Cv[(size_t)(row + r) * N + col] = acc[mi][ni][r] + bvv;
    }
  }
}

// ---------------- flash attention v9: LDS-staged K, single-buffer reg V ----
// (unchanged from round 4 — 104us, MfmaUtil 32 + VALUBusy 64 = issue-bound)
__global__ __launch_bounds__(256, 4) void attn9(const unsigned short* __restrict__ Q,
                                                const unsigned short* __restrict__ K,
                                                const unsigned short* __restrict__ Vt,
                                                unsigned short* __restrict__ X) {
  __shared__ unsigned short Ks[2][128 * 64];  // 2 x 16 KB, XOR-swizzled content
  const int tid = threadIdx.x, lane = tid & 63, w = tid >> 6;
  const int quad = lane >> 4, ln = lane & 15;
  const int bh = blockIdx.x, b = bh >> 4, h = bh & 15;
  const size_t base = (size_t)b * SEQ * HIDDEN + (size_t)h * HDIM;
  const unsigned short* Qh = Q + base;
  const unsigned short* Kh = K + base;
  const unsigned short* vtile = Vt + (size_t)bh * 16 * 8192;
  const int qw = blockIdx.y * 128 + w * 32;

  // K DMA: thread covers 16B chunks {tid + s*256}, s=0..3. chunk c: row=c>>3,
  // cb=c&7. LDS dest = linear c*16B (lane-linear per wave, as HW requires);
  // global source chunk = cb ^ (row&7)  (row&7 invariant across shots).
  const int kr0 = tid >> 3, kcb = tid & 7;
  const unsigned short* ksrc = Kh + (size_t)kr0 * HIDDEN + ((kcb ^ (kr0 & 7)) * 8);

  // swizzled K fragment read offsets (elems): row = mt*16+ln, chunk kk*4+quad
  const int krd0 = ln * 64 + ((quad ^ (ln & 7)) * 8);        // kk=0
  const int krd1 = ln * 64 + (((4 | quad) ^ (ln & 7)) * 8);  // kk=1

  // resident Q B-frags: B[k=d=kk2*32+quad*8+j][n=q=nt*16+ln]
  u16x8 qf[2][2];
#pragma unroll
  for (int nt = 0; nt < 2; nt++)
#pragma unroll
    for (int kk2 = 0; kk2 < 2; kk2++)
      qf[nt][kk2] = *(const u16x8*)(Qh + (size_t)(qw + nt * 16 + ln) * HIDDEN + kk2 * 32 + quad * 8);

  f32x4 o[4][2];
  f32x4 zero = {0.f, 0.f, 0.f, 0.f};
#pragma unroll
  for (int mtd = 0; mtd < 4; mtd++)
#pragma unroll
    for (int nt = 0; nt < 2; nt++) o[mtd][nt] = zero;
  f32x4 l2[2] = {zero, zero};

  u16x8 onesf;
#pragma unroll
  for (int j = 0; j < 8; j++) onesf[j] = 0x3F80;  // bf16 1.0

  // prologue: stage K(0) into buf0
  {
    unsigned short* kd = &Ks[0][tid * 8];
    gload_lds16(ksrc, kd);
    gload_lds16(ksrc + 32 * HIDDEN, kd + 2048);
    gload_lds16(ksrc + 64 * HIDDEN, kd + 4096);
    gload_lds16(ksrc + 96 * HIDDEN, kd + 6144);
  }

  for (int kt = 0; kt < 16; ++kt) {
    __syncthreads();  // drains own DMA (vmcnt0) -> K(kt) visible; buf swap safe
    const unsigned short* kb = &Ks[kt & 1][0];
    const unsigned short* vt = vtile + kt * 8192;
#pragma unroll
    for (int g = 0; g < 4; g++) {
      // V A-frags for this group: issued here, consumed after QK+exp2 (~450cy)
      u16x8 vp[4];
#pragma unroll
      for (int mtd = 0; mtd < 4; mtd++)
        vp[mtd] = *(const u16x8*)(vt + (g * 4 + mtd) * 512 + lane * 8);
      // K DMA for kt+1: issued after this tile's LAST V loads (vmcnt FIFO ->
      // PV's vp-wait, on older slots, never drains the younger DMA)
      if (g == 3 && kt < 15) {
        const unsigned short* ks = ksrc + (size_t)(kt + 1) * (128 * HIDDEN);
        unsigned short* kd = &Ks[(kt + 1) & 1][tid * 8];
        gload_lds16(ks, kd);
        gload_lds16(ks + 32 * HIDDEN, kd + 2048);
        gload_lds16(ks + 64 * HIDDEN, kd + 4096);
        gload_lds16(ks + 96 * HIDDEN, kd + 6144);
      }
      u32x4 P[2];
#pragma unroll
      for (int half = 0; half < 2; half++) {
        const int mt = 2 * g + half;
        const u16x8 kf0 = *(const u16x8*)&kb[mt * 1024 + krd0];
        const u16x8 kf1 = *(const u16x8*)&kb[mt * 1024 + krd1];
        f32x4 s0 = zero, s1 = zero;
        __builtin_amdgcn_s_setprio(1);
        s0 = __builtin_amdgcn_mfma_f32_16x16x32_bf16(
            __builtin_bit_cast(bf16x8, kf0), __builtin_bit_cast(bf16x8, qf[0][0]), s0, 0, 0, 0);
        s0 = __builtin_amdgcn_mfma_f32_16x16x32_bf16(
            __builtin_bit_cast(bf16x8, kf1), __builtin_bit_cast(bf16x8, qf[0][1]), s0, 0, 0, 0);
        s1 = __builtin_amdgcn_mfma_f32_16x16x32_bf16(
            __builtin_bit_cast(bf16x8, kf0), __builtin_bit_cast(bf16x8, qf[1][0]), s1, 0, 0, 0);
        s1 = __builtin_amdgcn_mfma_f32_16x16x32_bf16(
            __builtin_bit_cast(bf16x8, kf1), __builtin_bit_cast(bf16x8, qf[1][1]), s1, 0, 0, 0);
        __builtin_amdgcn_s_setprio(0);
        float e0[4], e1[4];
#pragma unroll
        for (int r = 0; r < 4; r++) {
          e0[r] = __builtin_exp2f(s0[r]);
          e1[r] = __builtin_exp2f(s1[r]);
        }
        if (half == 0) {
          P[0][0] = pkcvt(e0[0], e0[1]); P[0][1] = pkcvt(e0[2], e0[3]);
          P[1][0] = pkcvt(e1[0], e1[1]); P[1][1] = pkcvt(e1[2], e1[3]);
        } else {
          P[0][2] = pkcvt(e0[0], e0[1]); P[0][3] = pkcvt(e0[2], e0[3]);
          P[1][2] = pkcvt(e1[0], e1[1]); P[1][3] = pkcvt(e1[2], e1[3]);
        }
      }
      // PV + denominator for this 32-key group
      __builtin_amdgcn_s_setprio(1);
#pragma unroll
      for (int nt = 0; nt < 2; nt++) {
        bf16x8 pb = __builtin_bit_cast(bf16x8, P[nt]);
        l2[nt] = __builtin_amdgcn_mfma_f32_16x16x32_bf16(
            __builtin_bit_cast(bf16x8, onesf), pb, l2[nt], 0, 0, 0);
#pragma unroll
        for (int mtd = 0; mtd < 4; mtd++)
          o[mtd][nt] = __builtin_amdgcn_mfma_f32_16x16x32_bf16(
              __builtin_bit_cast(bf16x8, vp[mtd]), pb, o[mtd][nt], 0, 0, 0);
      }
      __builtin_amdgcn_s_setprio(0);
    }
  }

  // l2[nt] rows are all identical = full denominator for q-column ln
  float inv[2];
#pragma unroll
  for (int nt = 0; nt < 2; nt++) inv[nt] = 1.0f / l2[nt][0];

#pragma unroll
  for (int nt = 0; nt < 2; nt++) {
    unsigned short* dst = X + (size_t)(b * SEQ + qw + nt * 16 + ln) * HIDDEN + h * HDIM;
#pragma unroll
    for (int mtd = 0; mtd < 4; mtd++) {
      uint2 ov;
      ov.x = pkcvt(o[mtd][nt][0] * inv[nt], o[mtd][nt][1] * inv[nt]);
      ov.y = pkcvt(o[mtd][nt][2] * inv[nt], o[mtd][nt][3] * inv[nt]);
      *(uint2*)(dst + mtd * 16 + quad * 4) = ov;
    }
  }
}

// ---------------------------------------------------------------------------
extern "C" void kernel_launch(void* const* d_in, const int* in_sizes, int n_in,
                              void* d_out, int out_size, void* d_ws, size_t ws_size,
                              hipStream_t stream) {
  const float* q_in = (const float*)d_in[0];
  const float* k_in = (const float*)d_in[1];
  const float* v_in = (const float*)d_in[2];
  const float* wq = (const float*)d_in[3];
  const float* bq = (const float*)d_in[4];
  const float* wk = (const float*)d_in[5];
  const float* bk = (const float*)d_in[6];
  const float* wv = (const float*)d_in[7];
  const float* bv = (const float*)d_in[8];
  const float* wf = (const float*)d_in[9];
  const float* bfb = (const float*)d_in[10];

  const size_t NX = (size_t)MTOT * HIDDEN;
  const size_t NW = (size_t)HIDDEN * HIDDEN;
  unsigned short* A = (unsigned short*)d_ws;
  unsigned short* Bx = A + NX;
  unsigned short* C = Bx + NX;
  unsigned short* W4 = C + NX;
  unsigned short* Qb = W4 + 4 * NW;
  unsigned short* Kb = Qb + NX;
  unsigned short* Vtb = Kb + NX;  // fragment-linear Vt (written by gemm_qkv)

  cvt3<<<dim3(NX / 1024, 3), 256, 0, stream>>>(q_in, k_in, v_in, A, (int)NX);
  cvt4<<<dim3(NW / 1024, 4), 256, 0, stream>>>(wq, wk, wv, wf, W4, (int)NW);

  gemm_qkv<<<dim3(24, MTOT / 128), 256, 0, stream>>>(A, Bx, C, W4, bq, bk, bv, Qb, Kb, Vtb);
  attn9<<<dim3(NHEADS * 4, SEQ / 128), 256, 0, stream>>>(Qb, Kb, Vtb, C);
  gemm_f<<<dim3(8, MTOT / 128), 256, 0, stream>>>(C, W4 + 3 * NW, bfb, (float*)d_out);
}

// Round 7
// 348.865 us; speedup vs baseline: 1.0655x; 1.0655x over previous
//
#include <hip/hip_runtime.h>
#include <stdint.h>

#define SEQ 2048
#define HIDDEN 1024
#define NHEADS 16
#define HDIM 64
#define MTOT 8192  // B*SEQ

// 1/sqrt(HDIM) * log2(e), folded into wq/bq so attn does exp2(S) directly
#define C1SCALE 0.1803368801111437f

typedef __bf16 bf16x8 __attribute__((ext_vector_type(8)));
typedef unsigned short u16x8 __attribute__((ext_vector_type(8)));
typedef short s16x4 __attribute__((ext_vector_type(4)));
typedef unsigned int u32x4 __attribute__((ext_vector_type(4)));
typedef float f32x4 __attribute__((ext_vector_type(4)));

#define GAS __attribute__((address_space(1)))
#define LAS __attribute__((address_space(3)))

__device__ __forceinline__ unsigned short bf16_rne(float f) {
  union { float f; unsigned int u; } v; v.f = f;
  return (unsigned short)((v.u + 0x7fffu + ((v.u >> 16) & 1u)) >> 16);
}

// pack 2 f32 -> 2 bf16 (RNE) in one dword via v_cvt_pk_bf16_f32 (T12 recipe;
// no builtin on gfx950). D[15:0]=bf16(lo), D[31:16]=bf16(hi).
__device__ __forceinline__ unsigned int pkcvt(float lo, float hi) {
  unsigned int r;
  asm("v_cvt_pk_bf16_f32 %0, %1, %2" : "=v"(r) : "v"(lo), "v"(hi));
  return r;
}

__device__ __forceinline__ void gload_lds16(const unsigned short* g, unsigned short* l) {
  __builtin_amdgcn_global_load_lds((GAS void*)(unsigned short*)g, (LAS void*)l, 16, 0, 0);
}

// ---------------- fused fp32 -> bf16 conversions ---------------------------
__global__ __launch_bounds__(256) void cvt3(const float* __restrict__ a,
                                            const float* __restrict__ b,
                                            const float* __restrict__ c,
                                            unsigned short* __restrict__ out,
                                            int perSeg) {
  const int seg = blockIdx.y;
  const float* in = seg == 0 ? a : (seg == 1 ? b : c);
  int i = blockIdx.x * 256 + threadIdx.x;
  float4 v = ((const float4*)in)[i];
  ushort4 o;
  o.x = bf16_rne(v.x); o.y = bf16_rne(v.y);
  o.z = bf16_rne(v.z); o.w = bf16_rne(v.w);
  ((ushort4*)(out + (size_t)seg * perSeg))[i] = o;
}

// seg 0 (wq) is pre-scaled by C1SCALE (softmax scale folded into Q projection)
__global__ __launch_bounds__(256) void cvt4(const float* __restrict__ a,
                                            const float* __restrict__ b,
                                            const float* __restrict__ c,
                                            const float* __restrict__ d,
                                            unsigned short* __restrict__ out,
                                            int perSeg) {
  const int seg = blockIdx.y;
  const float* in = seg == 0 ? a : (seg == 1 ? b : (seg == 2 ? c : d));
  const float sc = (seg == 0) ? C1SCALE : 1.0f;
  int i = blockIdx.x * 256 + threadIdx.x;
  float4 v = ((const float4*)in)[i];
  ushort4 o;
  o.x = bf16_rne(v.x * sc); o.y = bf16_rne(v.y * sc);
  o.z = bf16_rne(v.z * sc); o.w = bf16_rne(v.w * sc);
  ((ushort4*)(out + (size_t)seg * perSeg))[i] = o;
}

// ---------------- fused QKV GEMM (v6) --------------------------------------
// R5 lesson: dbuf/latency-hiding was NULL -> GEMM was L2-thrash throughput-
// bound (R4 swizzle scattered 24n x 8m panels = ~10MB live vs 4MB L2/XCD).
// v6: NATURAL mapping. grid(24,64), XCD = flat%8 = bx%8 -> each XCD holds
// W np=bx%8 for 3 segs = 768KB (L2-resident); A streams m-major in sync.
// BK=64 K-steps with the attn9 staging scheme (proven, 0 bank conflicts):
// XOR-swizzled global source + linear LDS dest (rule #21) + swizzled
// ds_read_b128 (was an 8-way conflict with the [128][32] tile).
// Double-buffered, 1 barrier/step. LDS 64KB -> 2 blocks/CU; (256,2) cap.
__global__ __launch_bounds__(256, 2) void gemm_qkv(const unsigned short* __restrict__ Xq,
                                                   const unsigned short* __restrict__ Xk,
                                                   const unsigned short* __restrict__ Xv,
                                                   const unsigned short* __restrict__ W,
                                                   const float* __restrict__ bq,
                                                   const float* __restrict__ bk,
                                                   const float* __restrict__ bv,
                                                   unsigned short* __restrict__ Qb,
                                                   unsigned short* __restrict__ Kb,
                                                   unsigned short* __restrict__ Vt) {
  __shared__ unsigned short As[2][128 * 64];
  __shared__ unsigned short Bs[2][128 * 64];
  const int tid = threadIdx.x;
  const int lane = tid & 63, w = tid >> 6;
  const int quad = lane >> 4, ln = lane & 15;
  const int wm = w & 1, wn = w >> 1;
  const int nIdx = blockIdx.x;  // 0..23 ; XCD = nIdx%8 (24%8==0)
  const int mBase = blockIdx.y * 128, nBase = (nIdx & 7) * 128;
  const int seg = nIdx >> 3;
  const unsigned short* A = seg == 0 ? Xq : (seg == 1 ? Xk : Xv);
  const float* bias = seg == 0 ? bq : (seg == 1 ? bk : bv);
  const float bscale = seg == 0 ? C1SCALE : 1.0f;
  const int K = HIDDEN;

  f32x4 acc[4][4];
  f32x4 zero = {0.f, 0.f, 0.f, 0.f};
#pragma unroll
  for (int i = 0; i < 4; i++)
#pragma unroll
    for (int j = 0; j < 4; j++) acc[i][j] = zero;

  // staging: thread covers 16B chunks {tid + s*256}, s=0..3 per matrix.
  // chunk c: row = c>>3 (= sr + s*32), cb = c&7. LDS dest linear c*16B;
  // global source chunk = cb ^ (row&7)  ((row&7) invariant across s).
  const int sr = tid >> 3, scb = tid & 7;
  const int scol = (scb ^ (sr & 7)) * 8;
  const unsigned short* Asrc = A + (size_t)(mBase + sr) * K + scol;
  const unsigned short* Wsrc = W + (size_t)(seg * HIDDEN + nBase + sr) * K + scol;

  // swizzled fragment-read column offsets (elems): chunk (kk*4+quad)^(ln&7)
  const int sw0 = (quad ^ (ln & 7)) * 8;        // kk=0
  const int sw1 = ((4 | quad) ^ (ln & 7)) * 8;  // kk=1
  const int arow = wm * 64 + ln, brow = wn * 64 + ln;

#define QKV_STAGE(ks, buf)                                              \
  {                                                                     \
    unsigned short* ad = &As[buf][tid * 8];                             \
    unsigned short* bd = &Bs[buf][tid * 8];                             \
    const unsigned short* as_ = Asrc + (ks) * 64;                       \
    const unsigned short* ws_ = Wsrc + (ks) * 64;                       \
    _Pragma("unroll") for (int s = 0; s < 4; s++) {                     \
      gload_lds16(as_ + (size_t)(s * 32) * K, ad + s * 2048);           \
      gload_lds16(ws_ + (size_t)(s * 32) * K, bd + s * 2048);           \
    }                                                                   \
  }

  QKV_STAGE(0, 0);
  for (int k = 0; k < 16; ++k) {
    __syncthreads();  // drains stage(k) DMA (in flight through step k-1)
    const int cur = k & 1;
    if (k < 15) QKV_STAGE(k + 1, cur ^ 1);
    u16x8 af[2][4], bfr[2][4];
#pragma unroll
    for (int mi = 0; mi < 4; mi++) {
      af[0][mi] = *(const u16x8*)&As[cur][(arow + mi * 16) * 64 + sw0];
      af[1][mi] = *(const u16x8*)&As[cur][(arow + mi * 16) * 64 + sw1];
    }
#pragma unroll
    for (int ni = 0; ni < 4; ni++) {
      bfr[0][ni] = *(const u16x8*)&Bs[cur][(brow + ni * 16) * 64 + sw0];
      bfr[1][ni] = *(const u16x8*)&Bs[cur][(brow + ni * 16) * 64 + sw1];
    }
#pragma unroll
    for (int kk = 0; kk < 2; kk++)
#pragma unroll
      for (int mi = 0; mi < 4; mi++)
#pragma unroll
        for (int ni = 0; ni < 4; ni++)
          acc[mi][ni] = __builtin_amdgcn_mfma_f32_16x16x32_bf16(
              __builtin_bit_cast(bf16x8, af[kk][mi]), __builtin_bit_cast(bf16x8, bfr[kk][ni]),
              acc[mi][ni], 0, 0, 0);
  }
#undef QKV_STAGE

  if (seg < 2) {
    unsigned short* outp = seg == 0 ? Qb : Kb;
#pragma unroll
    for (int ni = 0; ni < 4; ni++) {
      const int col = nBase + wn * 64 + ni * 16 + ln;
      const float bvv = bias[col] * bscale;
#pragma unroll
      for (int mi = 0; mi < 4; mi++) {
        const int row = mBase + wm * 64 + mi * 16 + quad * 4;
#pragma unroll
        for (int r = 0; r < 4; r++)
          outp[(size_t)(row + r) * HIDDEN + col] = bf16_rne(acc[mi][ni][r] + bvv);
      }
    }
  } else {
    // fused Vt epilogue (fragment-linear, PV-permuted)
    const int b = mBase >> 11;
    const int kt = (mBase & 2047) >> 7;
    const int h = (nBase >> 6) + wn;
    unsigned short* tb = Vt + (((size_t)(b * NHEADS + h) * 16 + kt) * 8192) + lane * 8;
#pragma unroll
    for (int ni = 0; ni < 4; ni++) {
      const int col = nBase + wn * 64 + ni * 16 + ln;
      const float bvv = bias[col];
#pragma unroll
      for (int p = 0; p < 2; p++) {
        const int f = (wm * 2 + p) * 4 + ni;
        u32x4 ov;
        ov[0] = pkcvt(acc[2 * p][ni][0] + bvv, acc[2 * p][ni][1] + bvv);
        ov[1] = pkcvt(acc[2 * p][ni][2] + bvv, acc[2 * p][ni][3] + bvv);
        ov[2] = pkcvt(acc[2 * p + 1][ni][0] + bvv, acc[2 * p + 1][ni][1] + bvv);
        ov[3] = pkcvt(acc[2 * p + 1][ni][2] + bvv, acc[2 * p + 1][ni][3] + bvv);
        *(u32x4*)(tb + f * 512) = ov;
      }
    }
  }
}

// ---------------- final GEMM (fp32 out, v6 same structure) ------------------
// Natural mapping: grid(8,64) -> XCD = bx, one 256KB W-panel per XCD
// (L2-resident); A streams m-major in sync across XCDs.
__global__ __launch_bounds__(256, 2) void gemm_f(const unsigned short* __restrict__ A,
                                                 const unsigned short* __restrict__ W,
                                                 const float* __restrict__ bias,
                                                 float* __restrict__ Cv) {
  __shared__ unsigned short As[2][128 * 64];
  __shared__ unsigned short Bs[2][128 * 64];
  const int tid = threadIdx.x;
  const int lane = tid & 63, w = tid >> 6;
  const int quad = lane >> 4, ln = lane & 15;
  const int wm = w & 1, wn = w >> 1;
  const int mBase = blockIdx.y * 128, nBase = blockIdx.x * 128;
  const int K = HIDDEN, N = HIDDEN;

  f32x4 acc[4][4];
  f32x4 zero = {0.f, 0.f, 0.f, 0.f};
#pragma unroll
  for (int i = 0; i < 4; i++)
#pragma unroll
    for (int j = 0; j < 4; j++) acc[i][j] = zero;

  const int sr = tid >> 3, scb = tid & 7;
  const int scol = (scb ^ (sr & 7)) * 8;
  const unsigned short* Asrc = A + (size_t)(mBase + sr) * K + scol;
  const unsigned short* Wsrc = W + (size_t)(nBase + sr) * K + scol;

  const int sw0 = (quad ^ (ln & 7)) * 8;
  const int sw1 = ((4 | quad) ^ (ln & 7)) * 8;
  const int arow = wm * 64 + ln, brow = wn * 64 + ln;

#define F_STAGE(ks, buf)                                                \
  {                                                                     \
    unsigned short* ad = &As[buf][tid * 8];                             \
    unsigned short* bd = &Bs[buf][tid * 8];                             \
    const unsigned short* as_ = Asrc + (ks) * 64;                       \
    const unsigned short* ws_ = Wsrc + (ks) * 64;                       \
    _Pragma("unroll") for (int s = 0; s < 4; s++) {                     \
      gload_lds16(as_ + (size_t)(s * 32) * K, ad + s * 2048);           \
      gload_lds16(ws_ + (size_t)(s * 32) * K, bd + s * 2048);           \
    }                                                                   \
  }

  F_STAGE(0, 0);
  for (int k = 0; k < 16; ++k) {
    __syncthreads();
    const int cur = k & 1;
    if (k < 15) F_STAGE(k + 1, cur ^ 1);
    u16x8 af[2][4], bfr[2][4];
#pragma unroll
    for (int mi = 0; mi < 4; mi++) {
      af[0][mi] = *(const u16x8*)&As[cur][(arow + mi * 16) * 64 + sw0];
      af[1][mi] = *(const u16x8*)&As[cur][(arow + mi * 16) * 64 + sw1];
    }
#pragma unroll
    for (int ni = 0; ni < 4; ni++) {
      bfr[0][ni] = *(const u16x8*)&Bs[cur][(brow + ni * 16) * 64 + sw0];
      bfr[1][ni] = *(const u16x8*)&Bs[cur][(brow + ni * 16) * 64 + sw1];
    }
#pragma unroll
    for (int kk = 0; kk < 2; kk++)
#pragma unroll
      for (int mi = 0; mi < 4; mi++)
#pragma unroll
        for (int ni = 0; ni < 4; ni++)
          acc[mi][ni] = __builtin_amdgcn_mfma_f32_16x16x32_bf16(
              __builtin_bit_cast(bf16x8, af[kk][mi]), __builtin_bit_cast(bf16x8, bfr[kk][ni]),
              acc[mi][ni], 0, 0, 0);
  }
#undef F_STAGE

#pragma unroll
  for (int ni = 0; ni < 4; ni++) {
    const int col = nBase + wn * 64 + ni * 16 + ln;
    const float bvv = bias[col];
#pragma unroll
    for (int mi = 0; mi < 4; mi++) {
      const int row = mBase + wm * 64 + mi * 16 + quad * 4;
#pragma unroll
      for (int r = 0; r < 4; r++)
        Cv[(size_t)(row + r) * N + col] = acc[mi][ni][r] + bvv;
    }
  }
}

// ---------------- flash attention v9: LDS-staged K, single-buffer reg V ----
// (unchanged — 104us, MfmaUtil 32 + VALUBusy 65 = issue-bound)
__global__ __launch_bounds__(256, 4) void attn9(const unsigned short* __restrict__ Q,
                                                const unsigned short* __restrict__ K,
                                                const unsigned short* __restrict__ Vt,
                                                unsigned short* __restrict__ X) {
  __shared__ unsigned short Ks[2][128 * 64];  // 2 x 16 KB, XOR-swizzled content
  const int tid = threadIdx.x, lane = tid & 63, w = tid >> 6;
  const int quad = lane >> 4, ln = lane & 15;
  const int bh = blockIdx.x, b = bh >> 4, h = bh & 15;
  const size_t base = (size_t)b * SEQ * HIDDEN + (size_t)h * HDIM;
  const unsigned short* Qh = Q + base;
  const unsigned short* Kh = K + base;
  const unsigned short* vtile = Vt + (size_t)bh * 16 * 8192;
  const int qw = blockIdx.y * 128 + w * 32;

  const int kr0 = tid >> 3, kcb = tid & 7;
  const unsigned short* ksrc = Kh + (size_t)kr0 * HIDDEN + ((kcb ^ (kr0 & 7)) * 8);

  const int krd0 = ln * 64 + ((quad ^ (ln & 7)) * 8);        // kk=0
  const int krd1 = ln * 64 + (((4 | quad) ^ (ln & 7)) * 8);  // kk=1

  u16x8 qf[2][2];
#pragma unroll
  for (int nt = 0; nt < 2; nt++)
#pragma unroll
    for (int kk2 = 0; kk2 < 2; kk2++)
      qf[nt][kk2] = *(const u16x8*)(Qh + (size_t)(qw + nt * 16 + ln) * HIDDEN + kk2 * 32 + quad * 8);

  f32x4 o[4][2];
  f32x4 zero = {0.f, 0.f, 0.f, 0.f};
#pragma unroll
  for (int mtd = 0; mtd < 4; mtd++)
#pragma unroll
    for (int nt = 0; nt < 2; nt++) o[mtd][nt] = zero;
  f32x4 l2[2] = {zero, zero};

  u16x8 onesf;
#pragma unroll
  for (int j = 0; j < 8; j++) onesf[j] = 0x3F80;  // bf16 1.0

  {
    unsigned short* kd = &Ks[0][tid * 8];
    gload_lds16(ksrc, kd);
    gload_lds16(ksrc + 32 * HIDDEN, kd + 2048);
    gload_lds16(ksrc + 64 * HIDDEN, kd + 4096);
    gload_lds16(ksrc + 96 * HIDDEN, kd + 6144);
  }

  for (int kt = 0; kt < 16; ++kt) {
    __syncthreads();
    const unsigned short* kb = &Ks[kt & 1][0];
    const unsigned short* vt = vtile + kt * 8192;
#pragma unroll
    for (int g = 0; g < 4; g++) {
      u16x8 vp[4];
#pragma unroll
      for (int mtd = 0; mtd < 4; mtd++)
        vp[mtd] = *(const u16x8*)(vt + (g * 4 + mtd) * 512 + lane * 8);
      if (g == 3 && kt < 15) {
        const unsigned short* ks = ksrc + (size_t)(kt + 1) * (128 * HIDDEN);
        unsigned short* kd = &Ks[(kt + 1) & 1][tid * 8];
        gload_lds16(ks, kd);
        gload_lds16(ks + 32 * HIDDEN, kd + 2048);
        gload_lds16(ks + 64 * HIDDEN, kd + 4096);
        gload_lds16(ks + 96 * HIDDEN, kd + 6144);
      }
      u32x4 P[2];
#pragma unroll
      for (int half = 0; half < 2; half++) {
        const int mt = 2 * g + half;
        const u16x8 kf0 = *(const u16x8*)&kb[mt * 1024 + krd0];
        const u16x8 kf1 = *(const u16x8*)&kb[mt * 1024 + krd1];
        f32x4 s0 = zero, s1 = zero;
        __builtin_amdgcn_s_setprio(1);
        s0 = __builtin_amdgcn_mfma_f32_16x16x32_bf16(
            __builtin_bit_cast(bf16x8, kf0), __builtin_bit_cast(bf16x8, qf[0][0]), s0, 0, 0, 0);
        s0 = __builtin_amdgcn_mfma_f32_16x16x32_bf16(
            __builtin_bit_cast(bf16x8, kf1), __builtin_bit_cast(bf16x8, qf[0][1]), s0, 0, 0, 0);
        s1 = __builtin_amdgcn_mfma_f32_16x16x32_bf16(
            __builtin_bit_cast(bf16x8, kf0), __builtin_bit_cast(bf16x8, qf[1][0]), s1, 0, 0, 0);
        s1 = __builtin_amdgcn_mfma_f32_16x16x32_bf16(
            __builtin_bit_cast(bf16x8, kf1), __builtin_bit_cast(bf16x8, qf[1][1]), s1, 0, 0, 0);
        __builtin_amdgcn_s_setprio(0);
        float e0[4], e1[4];
#pragma unroll
        for (int r = 0; r < 4; r++) {
          e0[r] = __builtin_exp2f(s0[r]);
          e1[r] = __builtin_exp2f(s1[r]);
        }
        if (half == 0) {
          P[0][0] = pkcvt(e0[0], e0[1]); P[0][1] = pkcvt(e0[2], e0[3]);
          P[1][0] = pkcvt(e1[0], e1[1]); P[1][1] = pkcvt(e1[2], e1[3]);
        } else {
          P[0][2] = pkcvt(e0[0], e0[1]); P[0][3] = pkcvt(e0[2], e0[3]);
          P[1][2] = pkcvt(e1[0], e1[1]); P[1][3] = pkcvt(e1[2], e1[3]);
        }
      }
      __builtin_amdgcn_s_setprio(1);
#pragma unroll
      for (int nt = 0; nt < 2; nt++) {
        bf16x8 pb = __builtin_bit_cast(bf16x8, P[nt]);
        l2[nt] = __builtin_amdgcn_mfma_f32_16x16x32_bf16(
            __builtin_bit_cast(bf16x8, onesf), pb, l2[nt], 0, 0, 0);
#pragma unroll
        for (int mtd = 0; mtd < 4; mtd++)
          o[mtd][nt] = __builtin_amdgcn_mfma_f32_16x16x32_bf16(
              __builtin_bit_cast(bf16x8, vp[mtd]), pb, o[mtd][nt], 0, 0, 0);
      }
      __builtin_amdgcn_s_setprio(0);
    }
  }

  float inv[2];
#pragma unroll
  for (int nt = 0; nt < 2; nt++) inv[nt] = 1.0f / l2[nt][0];

#pragma unroll
  for (int nt = 0; nt < 2; nt++) {
    unsigned short* dst = X + (size_t)(b * SEQ + qw + nt * 16 + ln) * HIDDEN + h * HDIM;
#pragma unroll
    for (int mtd = 0; mtd < 4; mtd++) {
      uint2 ov;
      ov.x = pkcvt(o[mtd][nt][0] * inv[nt], o[mtd][nt][1] * inv[nt]);
      ov.y = pkcvt(o[mtd][nt][2] * inv[nt], o[mtd][nt][3] * inv[nt]);
      *(uint2*)(dst + mtd * 16 + quad * 4) = ov;
    }
  }
}

// ---------------------------------------------------------------------------
extern "C" void kernel_launch(void* const* d_in, const int* in_sizes, int n_in,
                              void* d_out, int out_size, void* d_ws, size_t ws_size,
                              hipStream_t stream) {
  const float* q_in = (const float*)d_in[0];
  const float* k_in = (const float*)d_in[1];
  const float* v_in = (const float*)d_in[2];
  const float* wq = (const float*)d_in[3];
  const float* bq = (const float*)d_in[4];
  const float* wk = (const float*)d_in[5];
  const float* bk = (const float*)d_in[6];
  const float* wv = (const float*)d_in[7];
  const float* bv = (const float*)d_in[8];
  const float* wf = (const float*)d_in[9];
  const float* bfb = (const float*)d_in[10];

  const size_t NX = (size_t)MTOT * HIDDEN;
  const size_t NW = (size_t)HIDDEN * HIDDEN;
  unsigned short* A = (unsigned short*)d_ws;
  unsigned short* Bx = A + NX;
  unsigned short* C = Bx + NX;
  unsigned short* W4 = C + NX;
  unsigned short* Qb = W4 + 4 * NW;
  unsigned short* Kb = Qb + NX;
  unsigned short* Vtb = Kb + NX;  // fragment-linear Vt (written by gemm_qkv)

  cvt3<<<dim3(NX / 1024, 3), 256, 0, stream>>>(q_in, k_in, v_in, A, (int)NX);
  cvt4<<<dim3(NW / 1024, 4), 256, 0, stream>>>(wq, wk, wv, wf, W4, (int)NW);

  gemm_qkv<<<dim3(24, MTOT / 128), 256, 0, stream>>>(A, Bx, C, W4, bq, bk, bv, Qb, Kb, Vtb);
  attn9<<<dim3(NHEADS * 4, SEQ / 128), 256, 0, stream>>>(Qb, Kb, Vtb, C);
  gemm_f<<<dim3(8, MTOT / 128), 256, 0, stream>>>(C, W4 + 3 * NW, bfb, (float*)d_out);
}